// Round 13
// baseline (382.916 us; speedup 1.0000x reference)
//
#include <hip/hip_runtime.h>
#include <math.h>

// ---------------------------------------------------------------------------
// GCN: 3 layers (128->32->32->32). CSR build with NO scattered global stores
// (hist/total/sbase/binoff/split/place, pairs PACKED: src<<9 | dst_local).
// Aggregation: COLUMN-SPLIT into two passes of 16 fp16 cols. Each pass's
// gather array is [N][16] fp16 = 3.2MB < 4MB XCD-L2 -> L2-resident gathers
// (the full [N][32] 6.4MB array thrashed the 4MB L2: ~60% hit, 53MB misses).
// 16-lane group per node, 16-deep batched 32B gathers, f32 accum.
// Algebra: agg[g] = tanh( dis[g]*(sum_{e:dst=g} hps[src_e] + hps[g]) + b ),
//          hps = dis ⊙ (h @ W). Layer 2/3 transform via k_gemmK<32> (LDS GEMM).
// Assumes N <= 128000; harness: N=100000, E=1.6M.
// ---------------------------------------------------------------------------

typedef int      int4v   __attribute__((ext_vector_type(4)));
typedef float    float4v __attribute__((ext_vector_type(4)));
typedef _Float16 half4v  __attribute__((ext_vector_type(4)));

#define NBLK 256            // blocks in hist/split
#define SB   500            // nodes per fine bin
#define CAPE 10240          // LDS stage capacity (bin mean 8000, std ~90)

// ---- per-block fine histogram: blk_hist[b*NP + f] ----
__global__ void k_hist(const int* __restrict__ dst, int* __restrict__ blk_hist,
                       int E, int NP) {
    __shared__ int h[256];
    for (int i = threadIdx.x; i < NP; i += 256) h[i] = 0;
    __syncthreads();
    const int4v* d4 = (const int4v*)dst;
    int nv = E >> 2;
    int stride = gridDim.x * blockDim.x;
    for (int i = blockIdx.x * blockDim.x + threadIdx.x; i < nv; i += stride) {
        int4v d = __builtin_nontemporal_load(&d4[i]);
#pragma unroll
        for (int j = 0; j < 4; ++j) atomicAdd(&h[d[j] / SB], 1);
    }
    if (blockIdx.x == 0) {
        for (int e = (nv << 2) + threadIdx.x; e < E; e += blockDim.x)
            atomicAdd(&h[dst[e] / SB], 1);
    }
    __syncthreads();
    for (int i = threadIdx.x; i < NP; i += 256)
        blk_hist[blockIdx.x * NP + i] = h[i];
}

__global__ void k_total(const int* __restrict__ blk_hist, int* __restrict__ total, int NP) {
    __shared__ int s[256];
    int f = blockIdx.x;
    int acc = 0;
    for (int b = threadIdx.x; b < NBLK; b += 256) acc += blk_hist[b * NP + f];
    s[threadIdx.x] = acc;
    __syncthreads();
    for (int off = 128; off > 0; off >>= 1) {
        if (threadIdx.x < off) s[threadIdx.x] += s[threadIdx.x + off];
        __syncthreads();
    }
    if (threadIdx.x == 0) total[f] = s[0];
}

__global__ void k_sbase(const int* __restrict__ total, int* __restrict__ sbase, int NP) {
    __shared__ int s[256];
    int t = threadIdx.x;
    int v = (t < NP) ? total[t] : 0;
    s[t] = v;
    __syncthreads();
    for (int off = 1; off < 256; off <<= 1) {
        int u = (t >= off) ? s[t - off] : 0;
        __syncthreads();
        s[t] += u;
        __syncthreads();
    }
    if (t < NP) sbase[t] = s[t] - v;
    if (t == NP - 1) sbase[NP] = s[t];
}

__global__ void k_binoff(const int* __restrict__ blk_hist, const int* __restrict__ sbase,
                         int* __restrict__ blk_off, int NP) {
    __shared__ int s[NBLK];
    int f = blockIdx.x;
    int b = threadIdx.x;
    int v = blk_hist[b * NP + f];
    s[b] = v;
    __syncthreads();
    for (int off = 1; off < NBLK; off <<= 1) {
        int u = (b >= off) ? s[b - off] : 0;
        __syncthreads();
        s[b] += u;
        __syncthreads();
    }
    blk_off[b * NP + f] = sbase[f] + s[b] - v;
}

__global__ void k_split(const int* __restrict__ src, const int* __restrict__ dst,
                        const int* __restrict__ blk_off, unsigned* __restrict__ pairs,
                        int E, int NP) {
    __shared__ int goff[256];
    for (int f = threadIdx.x; f < NP; f += 256)
        goff[f] = blk_off[blockIdx.x * NP + f];
    __syncthreads();
    const int4v* d4 = (const int4v*)dst;
    const int4v* s4 = (const int4v*)src;
    int nv = E >> 2;
    int stride = gridDim.x * blockDim.x;
    for (int i = blockIdx.x * blockDim.x + threadIdx.x; i < nv; i += stride) {
        int4v d = __builtin_nontemporal_load(&d4[i]);
        int4v s = __builtin_nontemporal_load(&s4[i]);
#pragma unroll
        for (int j = 0; j < 4; ++j) {
            int f = d[j] / SB;
            int pos = atomicAdd(&goff[f], 1);
            pairs[pos] = ((unsigned)s[j] << 9) | (unsigned)(d[j] - f * SB);
        }
    }
    if (blockIdx.x == 0) {
        for (int e = (nv << 2) + threadIdx.x; e < E; e += blockDim.x) {
            int f = dst[e] / SB;
            int pos = atomicAdd(&goff[f], 1);
            pairs[pos] = ((unsigned)src[e] << 9) | (unsigned)(dst[e] - f * SB);
        }
    }
}

__global__ void __launch_bounds__(512)
k_place(const unsigned* __restrict__ pairs, const int* __restrict__ sbase,
        int* __restrict__ rowptr, float* __restrict__ dis,
        int* __restrict__ csr_src, int N, int NP) {
    __shared__ int lcnt[SB];
    __shared__ int lrp[SB + 1];
    __shared__ int sc[512];
    __shared__ int stage[CAPE];
    int f = blockIdx.x;
    int lo = f * SB;
    if (lo >= N) return;
    int hi = lo + SB; if (hi > N) hi = N;
    int sbc = hi - lo;
    int p0 = sbase[f], p1 = sbase[f + 1];
    int base = p0;
    int tid = threadIdx.x;
    for (int i = tid; i < sbc; i += 512) lcnt[i] = 0;
    __syncthreads();
    {
        int i = p0 + tid;
        for (; i + 3 * 512 < p1; i += 4 * 512) {
            unsigned a = pairs[i], c = pairs[i + 512], d = pairs[i + 1024], e = pairs[i + 1536];
            atomicAdd(&lcnt[a & 511u], 1);
            atomicAdd(&lcnt[c & 511u], 1);
            atomicAdd(&lcnt[d & 511u], 1);
            atomicAdd(&lcnt[e & 511u], 1);
        }
        for (; i < p1; i += 512) atomicAdd(&lcnt[pairs[i] & 511u], 1);
    }
    __syncthreads();
    for (int i = tid; i < sbc; i += 512) dis[lo + i] = rsqrtf(1.0f + (float)lcnt[i]);
    int v = (tid < sbc) ? lcnt[tid] : 0;
    sc[tid] = v;
    __syncthreads();
    for (int off = 1; off < 512; off <<= 1) {
        int u = (tid >= off) ? sc[tid - off] : 0;
        __syncthreads();
        sc[tid] += u;
        __syncthreads();
    }
    if (tid < sbc) lrp[tid] = sc[tid] - v;
    if (tid == 511) lrp[sbc] = sc[511];
    __syncthreads();
    int T = lrp[sbc];
    for (int i = tid; i < sbc; i += 512) rowptr[lo + i] = base + lrp[i];
    if (hi == N && tid == 0) rowptr[N] = base + T;
    for (int i = tid; i < sbc; i += 512) lcnt[i] = 0;
    __syncthreads();
    {
        int i = p0 + tid;
        for (; i + 3 * 512 < p1; i += 4 * 512) {
            unsigned pk[4] = { pairs[i], pairs[i + 512], pairs[i + 1024], pairs[i + 1536] };
#pragma unroll
            for (int j = 0; j < 4; ++j) {
                unsigned ly = pk[j] & 511u;
                int slot = lrp[ly] + atomicAdd(&lcnt[ly], 1);
                if (T <= CAPE) stage[slot] = (int)(pk[j] >> 9);
                else           csr_src[base + slot] = (int)(pk[j] >> 9);
            }
        }
        for (; i < p1; i += 512) {
            unsigned p = pairs[i];
            unsigned ly = p & 511u;
            int slot = lrp[ly] + atomicAdd(&lcnt[ly], 1);
            if (T <= CAPE) stage[slot] = (int)(p >> 9);
            else           csr_src[base + slot] = (int)(p >> 9);
        }
    }
    __syncthreads();
    if (T <= CAPE)
        for (int j = tid; j < T; j += 512) csr_src[base + j] = stage[j];
}

// ---- GEMM: {hA,hB}[n][16] = fp16( dis ⊙ (h[n, K cols of ldh] @ W[K,32]) ) ----
// 128 threads, 64 rows/block, register 4x4 tile. Cols 0-15 -> hA, 16-31 -> hB.
template <int K>
__global__ void k_gemmK(const float* __restrict__ h, int ldh, const float* __restrict__ W,
                        const float* __restrict__ dis, _Float16* __restrict__ hA,
                        _Float16* __restrict__ hB, int n) {
    __shared__ float sW[K * 32];
    __shared__ float sh[64 * (K + 4)];
    const int KP = K + 4;
    int tid = threadIdx.x;
    int row0 = blockIdx.x * 64;
    for (int j = tid; j < K * 8; j += 128)
        *(float4*)&sW[j * 4] = *(const float4*)&W[j * 4];
    for (int j = tid; j < 16 * K; j += 128) {
        int r = j / (K / 4), c4 = j % (K / 4);
        float4v v = {0.f, 0.f, 0.f, 0.f};
        if (row0 + r < n)
            v = __builtin_nontemporal_load((const float4v*)&h[(size_t)(row0 + r) * ldh + c4 * 4]);
        *(float4v*)&sh[r * KP + c4 * 4] = v;
    }
    __syncthreads();
    int rg = tid >> 3;      // 0..15 -> 4 rows each
    int cg = tid & 7;       // 0..7  -> 4 cols each
    float acc[4][4] = {};
    const float* shp = &sh[(rg * 4) * KP];
    const float* swp = &sW[cg * 4];
#pragma unroll 8
    for (int k4 = 0; k4 < K / 4; ++k4) {
        float4 hv[4], wv[4];
#pragma unroll
        for (int r = 0; r < 4; ++r) hv[r] = *(const float4*)&shp[r * KP + k4 * 4];
#pragma unroll
        for (int t = 0; t < 4; ++t) wv[t] = *(const float4*)&swp[(k4 * 4 + t) * 32];
#pragma unroll
        for (int r = 0; r < 4; ++r) {
            const float hr[4] = {hv[r].x, hv[r].y, hv[r].z, hv[r].w};
#pragma unroll
            for (int t = 0; t < 4; ++t) {
                acc[r][0] += hr[t] * wv[t].x;
                acc[r][1] += hr[t] * wv[t].y;
                acc[r][2] += hr[t] * wv[t].z;
                acc[r][3] += hr[t] * wv[t].w;
            }
        }
    }
#pragma unroll
    for (int r = 0; r < 4; ++r) {
        int row = row0 + rg * 4 + r;
        if (row < n) {
            float dv = dis[row];
            half4v o = { (_Float16)(acc[r][0] * dv), (_Float16)(acc[r][1] * dv),
                         (_Float16)(acc[r][2] * dv), (_Float16)(acc[r][3] * dv) };
            if (cg < 4) *(half4v*)&hA[(size_t)row * 16 + cg * 4] = o;
            else        *(half4v*)&hB[(size_t)row * 16 + (cg - 4) * 4] = o;
        }
    }
}

// ---- half-row aggregation: 16-lane group per node, 32B fp16 gathers ----
// Gather array is [n][16] fp16 = 3.2MB -> resident in each XCD's 4MB L2.
__global__ void k_agg16(const _Float16* __restrict__ hp, const int* __restrict__ rowptr,
                        const int* __restrict__ csr_src, const float* __restrict__ dis,
                        const float* __restrict__ bias, float* __restrict__ outc, int n) {
    int g    = (blockIdx.x * blockDim.x + threadIdx.x) >> 4;
    int lane = threadIdx.x & 15;
    if (g >= n) return;
    float acc = (float)hp[(size_t)g * 16 + lane];   // self term
    int e0 = rowptr[g], e1 = rowptr[g + 1];
    int e = e0;
    while (e < e1) {
        int m = e1 - e; if (m > 16) m = 16;
        int sv = (e + lane < e1) ? __builtin_nontemporal_load(&csr_src[e + lane]) : 0;
        int k = 0;
        for (; k + 16 <= m; k += 16) {
            float v[16];
#pragma unroll
            for (int j = 0; j < 16; ++j) {
                int s = __shfl(sv, k + j, 16);
                v[j] = (float)hp[(size_t)s * 16 + lane];
            }
            float a = ((v[0] + v[1]) + (v[2] + v[3])) + ((v[4] + v[5]) + (v[6] + v[7]));
            float b = ((v[8] + v[9]) + (v[10] + v[11])) + ((v[12] + v[13]) + (v[14] + v[15]));
            acc += a + b;
        }
        for (; k + 8 <= m; k += 8) {
            float v[8];
#pragma unroll
            for (int j = 0; j < 8; ++j) {
                int s = __shfl(sv, k + j, 16);
                v[j] = (float)hp[(size_t)s * 16 + lane];
            }
            acc += ((v[0] + v[1]) + (v[2] + v[3])) + ((v[4] + v[5]) + (v[6] + v[7]));
        }
        if (k + 4 <= m) {
            float v[4];
#pragma unroll
            for (int j = 0; j < 4; ++j) {
                int s = __shfl(sv, k + j, 16);
                v[j] = (float)hp[(size_t)s * 16 + lane];
            }
            acc += (v[0] + v[1]) + (v[2] + v[3]);
            k += 4;
        }
        for (; k < m; ++k) {
            int s = __shfl(sv, k, 16);
            acc += (float)hp[(size_t)s * 16 + lane];
        }
        e += m;
    }
    float v = tanhf(dis[g] * acc + bias[lane]);
    __builtin_nontemporal_store(v, &outc[(size_t)g * 96 + lane]);
}

__global__ void k_idx(const int* __restrict__ batch, int* __restrict__ idx, int n, int g) {
    int i = blockIdx.x * blockDim.x + threadIdx.x;
    if (i >= g) return;
    int lo = 0, hi = n;
    while (lo < hi) {
        int mid = (lo + hi) >> 1;
        if (batch[mid] < i) lo = mid + 1; else hi = mid;
    }
    idx[i] = lo;
}

__global__ void k_head(const float* __restrict__ cat, const int* __restrict__ idx,
                       const float* __restrict__ w1, const float* __restrict__ b1,
                       const float* __restrict__ w2, const float* __restrict__ b2,
                       float* __restrict__ out) {
    __shared__ float gv[96];
    __shared__ float s0[128];
    __shared__ float s1[128];
    int g = blockIdx.x, t = threadIdx.x;
    int node = idx[g];
    if (t < 96) gv[t] = cat[(size_t)node * 96 + t];
    __syncthreads();
    float acc = b1[t];
#pragma unroll 8
    for (int i = 0; i < 96; ++i) acc += gv[i] * w1[i * 128 + t];
    float h = fmaxf(acc, 0.0f);
    s0[t] = h * w2[t * 2 + 0];
    s1[t] = h * w2[t * 2 + 1];
    __syncthreads();
    for (int off = 64; off > 0; off >>= 1) {
        if (t < off) { s0[t] += s0[t + off]; s1[t] += s1[t + off]; }
        __syncthreads();
    }
    if (t == 0) {
        float l0 = s0[0] + b2[0];
        float l1 = s1[0] + b2[1];
        float m  = fmaxf(l0, l1);
        float lse = m + logf(expf(l0 - m) + expf(l1 - m));
        out[(size_t)g * 2 + 0] = l0 - lse;
        out[(size_t)g * 2 + 1] = l1 - lse;
    }
}

extern "C" void kernel_launch(void* const* d_in, const int* in_sizes, int n_in,
                              void* d_out, int out_size, void* d_ws, size_t ws_size,
                              hipStream_t stream) {
    const float* x    = (const float*)d_in[0];
    const int*   ei   = (const int*)d_in[1];
    const int*   batch= (const int*)d_in[2];
    const float* W1   = (const float*)d_in[4];
    const float* b1   = (const float*)d_in[5];
    const float* W2   = (const float*)d_in[6];
    const float* b2   = (const float*)d_in[7];
    const float* W3   = (const float*)d_in[8];
    const float* b3   = (const float*)d_in[9];
    const float* l1w  = (const float*)d_in[10];
    const float* l1b  = (const float*)d_in[11];
    const float* l2w  = (const float*)d_in[12];
    const float* l2b  = (const float*)d_in[13];
    float* out = (float*)d_out;

    const int N = in_sizes[0] / 128;
    const int E = in_sizes[1] / 2;
    const int G = out_size / 2;
    const int* src = ei;
    const int* dst = ei + E;

    const int NP = (N + SB - 1) / SB;     // fine-bin count (=200 for N=100000)

    char* w = (char*)d_ws;
    auto alloc = [&](size_t bytes) {
        char* p = w;
        w += (bytes + 255) & ~(size_t)255;
        return p;
    };
    float*    dis      = (float*)   alloc((size_t)N * 4);
    int*      rowptr   = (int*)     alloc((size_t)(N + 1) * 4);
    int*      csr_src  = (int*)     alloc((size_t)E * 4);
    int*      blk_hist = (int*)     alloc((size_t)NBLK * NP * 4);
    int*      total    = (int*)     alloc((size_t)NP * 4);
    int*      sbase    = (int*)     alloc((size_t)(NP + 1) * 4);
    int*      blk_off  = (int*)     alloc((size_t)NBLK * NP * 4);
    unsigned* pairs    = (unsigned*)alloc((size_t)E * 4);
    _Float16* hA0      = (_Float16*)alloc((size_t)N * 16 * 2);
    _Float16* hB0      = (_Float16*)alloc((size_t)N * 16 * 2);
    _Float16* hA1      = (_Float16*)alloc((size_t)N * 16 * 2);
    _Float16* hB1      = (_Float16*)alloc((size_t)N * 16 * 2);
    float*    catb     = (float*)   alloc((size_t)N * 96 * 4);
    int*      idx      = (int*)     alloc((size_t)G * 4);

    const int nodes16_bl = (N * 16 + 255) / 256;   // 16 nodes per 256-thr block
    const int gemm_bl    = (N + 63) / 64;

    k_hist  <<<NBLK, 256, 0, stream>>>(dst, blk_hist, E, NP);
    k_total <<<NP,   256, 0, stream>>>(blk_hist, total, NP);
    k_sbase <<<1,    256, 0, stream>>>(total, sbase, NP);
    k_binoff<<<NP,  NBLK, 0, stream>>>(blk_hist, sbase, blk_off, NP);
    k_split <<<NBLK, 256, 0, stream>>>(src, dst, blk_off, pairs, E, NP);
    k_place <<<NP,   512, 0, stream>>>(pairs, sbase, rowptr, dis, csr_src, N, NP);

    // layer 1
    k_gemmK<128><<<gemm_bl, 128, 0, stream>>>(x, 128, W1, dis, hA0, hB0, N);
    k_agg16<<<nodes16_bl, 256, 0, stream>>>(hA0, rowptr, csr_src, dis, b1 + 0,  catb + 0,  N);
    k_agg16<<<nodes16_bl, 256, 0, stream>>>(hB0, rowptr, csr_src, dis, b1 + 16, catb + 16, N);
    // layer 2
    k_gemmK<32><<<gemm_bl, 128, 0, stream>>>(catb + 0, 96, W2, dis, hA1, hB1, N);
    k_agg16<<<nodes16_bl, 256, 0, stream>>>(hA1, rowptr, csr_src, dis, b2 + 0,  catb + 32, N);
    k_agg16<<<nodes16_bl, 256, 0, stream>>>(hB1, rowptr, csr_src, dis, b2 + 16, catb + 48, N);
    // layer 3
    k_gemmK<32><<<gemm_bl, 128, 0, stream>>>(catb + 32, 96, W3, dis, hA0, hB0, N);
    k_agg16<<<nodes16_bl, 256, 0, stream>>>(hA0, rowptr, csr_src, dis, b3 + 0,  catb + 64, N);
    k_agg16<<<nodes16_bl, 256, 0, stream>>>(hB0, rowptr, csr_src, dis, b3 + 16, catb + 80, N);

    k_idx<<<(G + 255) / 256, 256, 0, stream>>>(batch, idx, N, G);
    k_head<<<G, 128, 0, stream>>>(catb, idx, l1w, l1b, l2w, l2b, out);
}

// Round 14
// 228.368 us; speedup vs baseline: 1.6767x; 1.6767x over previous
//
#include <hip/hip_runtime.h>
#include <math.h>

// ---------------------------------------------------------------------------
// GCN: 3 layers (128->32->32->32). CSR build with NO scattered global stores
// (hist/total/sbase/binoff/split/place, pairs PACKED: src<<9 | dst_local).
// Aggregation: fp16 hps row-gather (64B/edge), 32-lane group per node,
// 16-deep batched gathers; layer-2/3 GEMM fused into agg epilogue.
// MEASURED FLOOR: agg = ~53us/layer across f32/fp16/half-row/sliced variants
// -> random 64B-granule gather fabric at ~2TB/s effective; graph is uniform
// random (no locality), so this is structural. Build kernels are the only
// non-floor cost: hist/split get 512 blocks (2/CU) + wave-private histograms.
// Algebra: agg[g] = tanh( dis[g]*(sum_{e:dst=g} hps[src_e] + hps[g]) + b ),
//          hps = dis ⊙ (h @ W).
// Assumes N <= 128000; harness: N=100000, E=1.6M.
// ---------------------------------------------------------------------------

typedef int      int4v   __attribute__((ext_vector_type(4)));
typedef float    float4v __attribute__((ext_vector_type(4)));
typedef _Float16 half4v  __attribute__((ext_vector_type(4)));

#define NBLK 512            // blocks in hist/split (2 per CU)
#define SB   500            // nodes per fine bin
#define CAPE 10240          // LDS stage capacity (bin mean 8000, std ~90)

// ---- per-block fine histogram, wave-privatized: blk_hist[b*NP + f] ----
__global__ void k_hist(const int* __restrict__ dst, int* __restrict__ blk_hist,
                       int E, int NP) {
    __shared__ int h[4 * 256];
    for (int i = threadIdx.x; i < 4 * NP; i += 256) h[i] = 0;
    __syncthreads();
    int wid = threadIdx.x >> 6;           // wave id 0..3
    int* hw = &h[wid * NP];
    const int4v* d4 = (const int4v*)dst;
    int nv = E >> 2;
    int stride = gridDim.x * blockDim.x;
    for (int i = blockIdx.x * blockDim.x + threadIdx.x; i < nv; i += stride) {
        int4v d = __builtin_nontemporal_load(&d4[i]);
#pragma unroll
        for (int j = 0; j < 4; ++j) atomicAdd(&hw[d[j] / SB], 1);
    }
    if (blockIdx.x == 0) {
        for (int e = (nv << 2) + threadIdx.x; e < E; e += blockDim.x)
            atomicAdd(&hw[dst[e] / SB], 1);
    }
    __syncthreads();
    for (int f = threadIdx.x; f < NP; f += 256)
        blk_hist[blockIdx.x * NP + f] = h[f] + h[NP + f] + h[2 * NP + f] + h[3 * NP + f];
}

// ---- per-bin totals ----
__global__ void k_total(const int* __restrict__ blk_hist, int* __restrict__ total, int NP) {
    __shared__ int s[256];
    int f = blockIdx.x;
    int acc = 0;
    for (int b = threadIdx.x; b < NBLK; b += 256) acc += blk_hist[b * NP + f];
    s[threadIdx.x] = acc;
    __syncthreads();
    for (int off = 128; off > 0; off >>= 1) {
        if (threadIdx.x < off) s[threadIdx.x] += s[threadIdx.x + off];
        __syncthreads();
    }
    if (threadIdx.x == 0) total[f] = s[0];
}

// ---- exclusive scan of totals -> sbase[0..NP] ----
__global__ void k_sbase(const int* __restrict__ total, int* __restrict__ sbase, int NP) {
    __shared__ int s[256];
    int t = threadIdx.x;
    int v = (t < NP) ? total[t] : 0;
    s[t] = v;
    __syncthreads();
    for (int off = 1; off < 256; off <<= 1) {
        int u = (t >= off) ? s[t - off] : 0;
        __syncthreads();
        s[t] += u;
        __syncthreads();
    }
    if (t < NP) sbase[t] = s[t] - v;
    if (t == NP - 1) sbase[NP] = s[t];
}

// ---- per-(block,bin) window offsets (NBLK threads, scan over blocks) ----
__global__ void k_binoff(const int* __restrict__ blk_hist, const int* __restrict__ sbase,
                         int* __restrict__ blk_off, int NP) {
    __shared__ int s[NBLK];
    int f = blockIdx.x;
    int b = threadIdx.x;
    int v = blk_hist[b * NP + f];
    s[b] = v;
    __syncthreads();
    for (int off = 1; off < NBLK; off <<= 1) {
        int u = (b >= off) ? s[b - off] : 0;
        __syncthreads();
        s[b] += u;
        __syncthreads();
    }
    blk_off[b * NP + f] = sbase[f] + s[b] - v;
}

// ---- scatter PACKED edges ((src<<9)|dst_local) into fine-bin regions ----
__global__ void k_split(const int* __restrict__ src, const int* __restrict__ dst,
                        const int* __restrict__ blk_off, unsigned* __restrict__ pairs,
                        int E, int NP) {
    __shared__ int goff[256];
    for (int f = threadIdx.x; f < NP; f += 256)
        goff[f] = blk_off[blockIdx.x * NP + f];
    __syncthreads();
    const int4v* d4 = (const int4v*)dst;
    const int4v* s4 = (const int4v*)src;
    int nv = E >> 2;
    int stride = gridDim.x * blockDim.x;
    for (int i = blockIdx.x * blockDim.x + threadIdx.x; i < nv; i += stride) {
        int4v d = __builtin_nontemporal_load(&d4[i]);
        int4v s = __builtin_nontemporal_load(&s4[i]);
#pragma unroll
        for (int j = 0; j < 4; ++j) {
            int f = d[j] / SB;
            int pos = atomicAdd(&goff[f], 1);
            pairs[pos] = ((unsigned)s[j] << 9) | (unsigned)(d[j] - f * SB);
        }
    }
    if (blockIdx.x == 0) {
        for (int e = (nv << 2) + threadIdx.x; e < E; e += blockDim.x) {
            int f = dst[e] / SB;
            int pos = atomicAdd(&goff[f], 1);
            pairs[pos] = ((unsigned)src[e] << 9) | (unsigned)(dst[e] - f * SB);
        }
    }
}

// ---- place: per fine bin, LDS count/scan/scatter, coalesced global writes ----
__global__ void __launch_bounds__(512)
k_place(const unsigned* __restrict__ pairs, const int* __restrict__ sbase,
        int* __restrict__ rowptr, float* __restrict__ dis,
        int* __restrict__ csr_src, int N, int NP) {
    __shared__ int lcnt[SB];
    __shared__ int lrp[SB + 1];
    __shared__ int sc[512];
    __shared__ int stage[CAPE];
    int f = blockIdx.x;
    int lo = f * SB;
    if (lo >= N) return;
    int hi = lo + SB; if (hi > N) hi = N;
    int sbc = hi - lo;
    int p0 = sbase[f], p1 = sbase[f + 1];
    int base = p0;
    int tid = threadIdx.x;
    for (int i = tid; i < sbc; i += 512) lcnt[i] = 0;
    __syncthreads();
    // pass A: count
    {
        int i = p0 + tid;
        for (; i + 3 * 512 < p1; i += 4 * 512) {
            unsigned a = pairs[i], c = pairs[i + 512], d = pairs[i + 1024], e = pairs[i + 1536];
            atomicAdd(&lcnt[a & 511u], 1);
            atomicAdd(&lcnt[c & 511u], 1);
            atomicAdd(&lcnt[d & 511u], 1);
            atomicAdd(&lcnt[e & 511u], 1);
        }
        for (; i < p1; i += 512) atomicAdd(&lcnt[pairs[i] & 511u], 1);
    }
    __syncthreads();
    // dis (coalesced)
    for (int i = tid; i < sbc; i += 512) dis[lo + i] = rsqrtf(1.0f + (float)lcnt[i]);
    // exclusive scan lcnt -> lrp
    int v = (tid < sbc) ? lcnt[tid] : 0;
    sc[tid] = v;
    __syncthreads();
    for (int off = 1; off < 512; off <<= 1) {
        int u = (tid >= off) ? sc[tid - off] : 0;
        __syncthreads();
        sc[tid] += u;
        __syncthreads();
    }
    if (tid < sbc) lrp[tid] = sc[tid] - v;
    if (tid == 511) lrp[sbc] = sc[511];
    __syncthreads();
    int T = lrp[sbc];
    // rowptr (coalesced)
    for (int i = tid; i < sbc; i += 512) rowptr[lo + i] = base + lrp[i];
    if (hi == N && tid == 0) rowptr[N] = base + T;
    // pass B: scatter into LDS stage (or global fallback if T > CAPE)
    for (int i = tid; i < sbc; i += 512) lcnt[i] = 0;
    __syncthreads();
    {
        int i = p0 + tid;
        for (; i + 3 * 512 < p1; i += 4 * 512) {
            unsigned pk[4] = { pairs[i], pairs[i + 512], pairs[i + 1024], pairs[i + 1536] };
#pragma unroll
            for (int j = 0; j < 4; ++j) {
                unsigned ly = pk[j] & 511u;
                int slot = lrp[ly] + atomicAdd(&lcnt[ly], 1);
                if (T <= CAPE) stage[slot] = (int)(pk[j] >> 9);
                else           csr_src[base + slot] = (int)(pk[j] >> 9);
            }
        }
        for (; i < p1; i += 512) {
            unsigned p = pairs[i];
            unsigned ly = p & 511u;
            int slot = lrp[ly] + atomicAdd(&lcnt[ly], 1);
            if (T <= CAPE) stage[slot] = (int)(p >> 9);
            else           csr_src[base + slot] = (int)(p >> 9);
        }
    }
    __syncthreads();
    if (T <= CAPE)
        for (int j = tid; j < T; j += 512) csr_src[base + j] = stage[j];
}

// ---- layer-1 GEMM: hps[n,32] = fp16( dis ⊙ (x[n,128] @ W[128,32]) ) ----
__global__ void k_gemm1(const float* __restrict__ h, const float* __restrict__ W,
                        const float* __restrict__ dis, _Float16* __restrict__ hps, int n) {
    __shared__ float sW[128 * 32];          // [k][col]
    __shared__ float sh[64 * 132];          // [row][k], pad 132
    int tid = threadIdx.x;
    int row0 = blockIdx.x * 64;
    for (int j = tid; j < 1024; j += 128)
        *(float4*)&sW[j * 4] = *(const float4*)&W[j * 4];
    for (int j = tid; j < 2048; j += 128) {
        int r = j >> 5, c4 = j & 31;
        float4v v = {0.f, 0.f, 0.f, 0.f};
        if (row0 + r < n)
            v = __builtin_nontemporal_load((const float4v*)&h[(size_t)(row0 + r) * 128 + c4 * 4]);
        *(float4v*)&sh[r * 132 + c4 * 4] = v;
    }
    __syncthreads();
    int rg = tid >> 3;      // 0..15 -> 4 rows each
    int cg = tid & 7;       // 0..7  -> 4 cols each
    float acc[4][4] = {};
    const float* shp = &sh[(rg * 4) * 132];
    const float* swp = &sW[cg * 4];
#pragma unroll 8
    for (int k4 = 0; k4 < 32; ++k4) {
        float4 hv[4], wv[4];
#pragma unroll
        for (int r = 0; r < 4; ++r) hv[r] = *(const float4*)&shp[r * 132 + k4 * 4];
#pragma unroll
        for (int t = 0; t < 4; ++t) wv[t] = *(const float4*)&swp[(k4 * 4 + t) * 32];
#pragma unroll
        for (int r = 0; r < 4; ++r) {
            const float hr[4] = {hv[r].x, hv[r].y, hv[r].z, hv[r].w};
#pragma unroll
            for (int t = 0; t < 4; ++t) {
                acc[r][0] += hr[t] * wv[t].x;
                acc[r][1] += hr[t] * wv[t].y;
                acc[r][2] += hr[t] * wv[t].z;
                acc[r][3] += hr[t] * wv[t].w;
            }
        }
    }
#pragma unroll
    for (int r = 0; r < 4; ++r) {
        int row = row0 + rg * 4 + r;
        if (row < n) {
            float dv = dis[row];
            half4v o = { (_Float16)(acc[r][0] * dv), (_Float16)(acc[r][1] * dv),
                         (_Float16)(acc[r][2] * dv), (_Float16)(acc[r][3] * dv) };
            *(half4v*)&hps[(size_t)row * 32 + cg * 4] = o;
        }
    }
}

// ---- aggregation (+ optional fused next-layer GEMM epilogue) ----
// 32-lane group per node; 16-deep batched fp16 row gathers, f32 accum.
template <bool FUSE>
__global__ void k_agg(const _Float16* __restrict__ hps, const int* __restrict__ rowptr,
                      const int* __restrict__ csr_src, const float* __restrict__ dis,
                      const float* __restrict__ bias, float* __restrict__ outc,
                      int n, const float* __restrict__ Wn, _Float16* __restrict__ hpsn) {
    __shared__ float sW[32 * 32];
    if (FUSE) {
        for (int i = threadIdx.x; i < 1024; i += 256) sW[i] = Wn[i];
        __syncthreads();
    }
    int g    = (blockIdx.x * blockDim.x + threadIdx.x) >> 5;
    int lane = threadIdx.x & 31;
    if (g >= n) return;
    float acc = (float)hps[(size_t)g * 32 + lane];   // self term
    int e0 = rowptr[g], e1 = rowptr[g + 1];
    int e = e0;
    while (e < e1) {
        int m = e1 - e; if (m > 32) m = 32;
        int sv = (e + lane < e1) ? __builtin_nontemporal_load(&csr_src[e + lane]) : 0;
        int k = 0;
        for (; k + 16 <= m; k += 16) {
            float v[16];
#pragma unroll
            for (int j = 0; j < 16; ++j) {
                int s = __shfl(sv, k + j, 32);
                v[j] = (float)hps[(size_t)s * 32 + lane];
            }
            float a = ((v[0] + v[1]) + (v[2] + v[3])) + ((v[4] + v[5]) + (v[6] + v[7]));
            float b = ((v[8] + v[9]) + (v[10] + v[11])) + ((v[12] + v[13]) + (v[14] + v[15]));
            acc += a + b;
        }
        for (; k + 8 <= m; k += 8) {
            float v[8];
#pragma unroll
            for (int j = 0; j < 8; ++j) {
                int s = __shfl(sv, k + j, 32);
                v[j] = (float)hps[(size_t)s * 32 + lane];
            }
            acc += ((v[0] + v[1]) + (v[2] + v[3])) + ((v[4] + v[5]) + (v[6] + v[7]));
        }
        if (k + 4 <= m) {
            float v[4];
#pragma unroll
            for (int j = 0; j < 4; ++j) {
                int s = __shfl(sv, k + j, 32);
                v[j] = (float)hps[(size_t)s * 32 + lane];
            }
            acc += (v[0] + v[1]) + (v[2] + v[3]);
            k += 4;
        }
        for (; k < m; ++k) {
            int s = __shfl(sv, k, 32);
            acc += (float)hps[(size_t)s * 32 + lane];
        }
        e += m;
    }
    float dg = dis[g];
    float v = tanhf(dg * acc + bias[lane]);
    __builtin_nontemporal_store(v, &outc[(size_t)g * 96 + lane]);
    if (FUSE) {
        float a2 = 0.0f;
#pragma unroll
        for (int k = 0; k < 32; ++k)
            a2 += __shfl(v, k, 32) * sW[k * 32 + lane];
        hpsn[(size_t)g * 32 + lane] = (_Float16)(dg * a2);
    }
}

__global__ void k_idx(const int* __restrict__ batch, int* __restrict__ idx, int n, int g) {
    int i = blockIdx.x * blockDim.x + threadIdx.x;
    if (i >= g) return;
    int lo = 0, hi = n;
    while (lo < hi) {
        int mid = (lo + hi) >> 1;
        if (batch[mid] < i) lo = mid + 1; else hi = mid;
    }
    idx[i] = lo;
}

__global__ void k_head(const float* __restrict__ cat, const int* __restrict__ idx,
                       const float* __restrict__ w1, const float* __restrict__ b1,
                       const float* __restrict__ w2, const float* __restrict__ b2,
                       float* __restrict__ out) {
    __shared__ float gv[96];
    __shared__ float s0[128];
    __shared__ float s1[128];
    int g = blockIdx.x, t = threadIdx.x;
    int node = idx[g];
    if (t < 96) gv[t] = cat[(size_t)node * 96 + t];
    __syncthreads();
    float acc = b1[t];
#pragma unroll 8
    for (int i = 0; i < 96; ++i) acc += gv[i] * w1[i * 128 + t];
    float h = fmaxf(acc, 0.0f);
    s0[t] = h * w2[t * 2 + 0];
    s1[t] = h * w2[t * 2 + 1];
    __syncthreads();
    for (int off = 64; off > 0; off >>= 1) {
        if (t < off) { s0[t] += s0[t + off]; s1[t] += s1[t + off]; }
        __syncthreads();
    }
    if (t == 0) {
        float l0 = s0[0] + b2[0];
        float l1 = s1[0] + b2[1];
        float m  = fmaxf(l0, l1);
        float lse = m + logf(expf(l0 - m) + expf(l1 - m));
        out[(size_t)g * 2 + 0] = l0 - lse;
        out[(size_t)g * 2 + 1] = l1 - lse;
    }
}

extern "C" void kernel_launch(void* const* d_in, const int* in_sizes, int n_in,
                              void* d_out, int out_size, void* d_ws, size_t ws_size,
                              hipStream_t stream) {
    const float* x    = (const float*)d_in[0];
    const int*   ei   = (const int*)d_in[1];
    const int*   batch= (const int*)d_in[2];
    const float* W1   = (const float*)d_in[4];
    const float* b1   = (const float*)d_in[5];
    const float* W2   = (const float*)d_in[6];
    const float* b2   = (const float*)d_in[7];
    const float* W3   = (const float*)d_in[8];
    const float* b3   = (const float*)d_in[9];
    const float* l1w  = (const float*)d_in[10];
    const float* l1b  = (const float*)d_in[11];
    const float* l2w  = (const float*)d_in[12];
    const float* l2b  = (const float*)d_in[13];
    float* out = (float*)d_out;

    const int N = in_sizes[0] / 128;
    const int E = in_sizes[1] / 2;
    const int G = out_size / 2;
    const int* src = ei;
    const int* dst = ei + E;

    const int NP = (N + SB - 1) / SB;     // fine-bin count (=200 for N=100000)

    char* w = (char*)d_ws;
    auto alloc = [&](size_t bytes) {
        char* p = w;
        w += (bytes + 255) & ~(size_t)255;
        return p;
    };
    float*    dis      = (float*)   alloc((size_t)N * 4);
    int*      rowptr   = (int*)     alloc((size_t)(N + 1) * 4);
    int*      csr_src  = (int*)     alloc((size_t)E * 4);
    int*      blk_hist = (int*)     alloc((size_t)NBLK * NP * 4);
    int*      total    = (int*)     alloc((size_t)NP * 4);
    int*      sbase    = (int*)     alloc((size_t)(NP + 1) * 4);
    int*      blk_off  = (int*)     alloc((size_t)NBLK * NP * 4);
    unsigned* pairs    = (unsigned*)alloc((size_t)E * 4);
    _Float16* hpsA     = (_Float16*)alloc((size_t)N * 32 * 2);
    _Float16* hpsB     = (_Float16*)alloc((size_t)N * 32 * 2);
    float*    catb     = (float*)   alloc((size_t)N * 96 * 4);
    int*      idx      = (int*)     alloc((size_t)G * 4);

    const int nodes_bl = (N * 32 + 255) / 256;   // 8 nodes per 256-thr block
    const int gemm_bl  = (N + 63) / 64;

    k_hist  <<<NBLK, 256, 0, stream>>>(dst, blk_hist, E, NP);
    k_total <<<NP,   256, 0, stream>>>(blk_hist, total, NP);
    k_sbase <<<1,    256, 0, stream>>>(total, sbase, NP);
    k_binoff<<<NP,  NBLK, 0, stream>>>(blk_hist, sbase, blk_off, NP);
    k_split <<<NBLK, 256, 0, stream>>>(src, dst, blk_off, pairs, E, NP);
    k_place <<<NP,   512, 0, stream>>>(pairs, sbase, rowptr, dis, csr_src, N, NP);

    // layer 1 GEMM, then agg layers (2/3 GEMMs fused into agg epilogues)
    k_gemm1<<<gemm_bl, 128, 0, stream>>>(x, W1, dis, hpsA, N);
    k_agg<true ><<<nodes_bl, 256, 0, stream>>>(hpsA, rowptr, csr_src, dis, b1, catb + 0,  N, W2, hpsB);
    k_agg<true ><<<nodes_bl, 256, 0, stream>>>(hpsB, rowptr, csr_src, dis, b2, catb + 32, N, W3, hpsA);
    k_agg<false><<<nodes_bl, 256, 0, stream>>>(hpsA, rowptr, csr_src, dis, b3, catb + 64, N, nullptr, nullptr);

    k_idx<<<(G + 255) / 256, 256, 0, stream>>>(batch, idx, N, G);
    k_head<<<G, 128, 0, stream>>>(catb, idx, l1w, l1b, l2w, l2b, out);
}